// Round 21
// baseline (225.011 us; speedup 1.0000x reference)
//
#include <hip/hip_runtime.h>
#include <stdint.h>

// ---------------------------------------------------------------------------
// TokenAlignerOT: A = cos(X,Y); K = exp(10A); ONE unbalanced-Sinkhorn
// iteration; T = (log K)/10 * (u K v^T) + delta; out = T @ X.
// Round 21 = r20 (best, 198.3us) with scale-in-epilogue: GEMM1 consumes RAW
// bf16 X,Y and multiplies by sx[i]*sy[j] before exp (cos = dot*sx*sy). So
// the bf16 X copy and bf16 X^T copy are the same data -> fused prep_x reads
// X once (emits Xb + XTb + sumsq partials), replacing rownorm+transpose
// (144MB -> 112MB of prep traffic). XT writes 64B-contiguous via LDS tiles.
// GEMM1: 256x256 NT, 16x16x32, fused exp+rowsum+colsum (frozen core).
// GEMM2: 256Mx128N NT, 32x32x16 frag-pipelined, direct stores (frozen).
// Workspace: 96 MiB + 48 KiB of d_ws; Yb parks in d_out (dead before GEMM2).
// ---------------------------------------------------------------------------

typedef __attribute__((ext_vector_type(8))) __bf16 bf16x8;
typedef __attribute__((ext_vector_type(4))) float f32x4;
typedef __attribute__((ext_vector_type(16))) float f32x16;
typedef __attribute__((ext_vector_type(8))) unsigned short ushort8;
typedef __attribute__((ext_vector_type(4))) unsigned short ushort4v;

#define N_TOK 4096
#define D_EMB 2048
#define FI 0.009900990099009901f   /* reg_m/(reg_m+reg) = 0.001/0.101 */
#define LOG2A (-12.0f)             /* log2(1/4096) */

__device__ __forceinline__ unsigned short f2bf(float f) {
  union { float f; uint32_t u; } c; c.f = f;
  uint32_t r = (c.u + 0x7FFFu + ((c.u >> 16) & 1u)) >> 16;
  return (unsigned short)r;
}
__device__ __forceinline__ float bf2f(unsigned short h) {
  union { uint32_t u; float f; } c; c.u = ((uint32_t)h) << 16;
  return c.f;
}
__device__ __forceinline__ float pow_fi_of(float s) {
  return exp2f(FI * (LOG2A - log2f(s)));
}

// async global->LDS, 16 B per lane; LDS dest is wave-uniform base (+lane*16 HW)
typedef const __attribute__((address_space(1))) unsigned int* as1_u32p;
typedef __attribute__((address_space(3))) unsigned int* as3_u32p;
__device__ __forceinline__ void gload16(const void* g, void* l) {
  __builtin_amdgcn_global_load_lds((as1_u32p)g, (as3_u32p)l, 16, 0, 0);
}

// ---------- prep_y: Yb = bf16(raw Y); sy[row] = 1/max(||Y_row||,eps) -------
__global__ __launch_bounds__(256) void prep_y(
    const float* __restrict__ Y, unsigned short* __restrict__ Yb,
    float* __restrict__ sy) {
  const int row = blockIdx.x;
  const int t = threadIdx.x;
  const float* r = Y + (size_t)row * D_EMB;
  float4 a = *(const float4*)(r + t * 8);
  float4 b = *(const float4*)(r + t * 8 + 4);
  float s = a.x * a.x + a.y * a.y + a.z * a.z + a.w * a.w
          + b.x * b.x + b.y * b.y + b.z * b.z + b.w * b.w;
#pragma unroll
  for (int off = 32; off; off >>= 1) s += __shfl_xor(s, off);
  __shared__ float wsum[4];
  if ((t & 63) == 0) wsum[t >> 6] = s;
  __syncthreads();
  float tot = wsum[0] + wsum[1] + wsum[2] + wsum[3];
  ushort8 o;
  o[0] = f2bf(a.x); o[1] = f2bf(a.y); o[2] = f2bf(a.z); o[3] = f2bf(a.w);
  o[4] = f2bf(b.x); o[5] = f2bf(b.y); o[6] = f2bf(b.z); o[7] = f2bf(b.w);
  *(ushort8*)(Yb + (size_t)row * D_EMB + t * 8) = o;
  if (t == 0) sy[row] = 1.0f / fmaxf(sqrtf(tot), 1e-8f);
}

// ---------- prep_x: Xb = bf16(raw X), XTb = bf16(raw X)^T, ssx partials ----
// grid (2,128): block = 32 rows x 1024 cols. Per 32-col tile: coalesced load
// (8 thr/row x 16B), Xb write (8x8B=64B/row), LDS stash, transposed XT write
// (8 thr/d x 8B = 64B contiguous per XT row).
__global__ __launch_bounds__(256) void prep_x(
    const float* __restrict__ X, unsigned short* __restrict__ Xb,
    unsigned short* __restrict__ XTb, float* __restrict__ ssx) {
  __shared__ float tile[32][33];
  const int r0 = blockIdx.y * 32;
  const int c0 = blockIdx.x * 1024;
  const int t = threadIdx.x;
  const int row = t >> 3;        // 0..31
  const int cg = (t & 7) * 4;    // col-in-tile
  float ss = 0.0f;
  for (int ct = 0; ct < 1024; ct += 32) {
    const size_t gi = (size_t)(r0 + row) * D_EMB + c0 + ct + cg;
    float4 v = *(const float4*)(X + gi);
    ss += v.x * v.x + v.y * v.y + v.z * v.z + v.w * v.w;
    ushort4v xo;
    xo[0] = f2bf(v.x); xo[1] = f2bf(v.y); xo[2] = f2bf(v.z); xo[3] = f2bf(v.w);
    *(ushort4v*)(Xb + gi) = xo;
    tile[row][cg + 0] = v.x; tile[row][cg + 1] = v.y;
    tile[row][cg + 2] = v.z; tile[row][cg + 3] = v.w;
    __syncthreads();
    // XT: d = c0+ct+(t>>3); this thread covers rows r0+(t&7)*4 .. +3
    const int dd = t >> 3;
    const int rr = (t & 7) * 4;
    ushort4v o;
#pragma unroll
    for (int e = 0; e < 4; ++e) o[e] = f2bf(tile[rr + e][dd]);
    *(ushort4v*)(XTb + (size_t)(c0 + ct + dd) * N_TOK + r0 + rr) = o;
    __syncthreads();
  }
  ss += __shfl_xor(ss, 1); ss += __shfl_xor(ss, 2); ss += __shfl_xor(ss, 4);
  if ((t & 7) == 0) unsafeAtomicAdd(&ssx[r0 + row], ss);
}

// ============ GEMM1: 256x256 NT, 4 waves, 128x128/wave (frozen core) =======
// A,B are RAW bf16 X,Y; epilogue: cos = acc*sx[i]*sy[j];
// K = bf16(exp(10*cos)) + fused rowsum AND colsum atomics.
__global__ __launch_bounds__(256, 1) void gemm256w4(
    const unsigned short* __restrict__ Amat, const unsigned short* __restrict__ Bmat,
    int ldA, int ldB, int nt, int ldC,
    unsigned short* __restrict__ outKbf, float* __restrict__ rsum,
    float* __restrict__ csum, const float* __restrict__ ssx,
    const float* __restrict__ sy) {
  __shared__ alignas(16) char smem[131072];
  const int t = threadIdx.x;
  const int l = t & 63;
  const int w = t >> 6;  // 0..3

  const int nwg = gridDim.x * gridDim.y;
  const int lin = blockIdx.y * gridDim.x + blockIdx.x;
  const int lin2 = (lin & 7) * (nwg >> 3) + (lin >> 3);
  const int bx = lin2 % gridDim.x;
  const int by = lin2 / gridDim.x;
  const int bM = by * 256;
  const int bN = bx * 256;
  const int wrow = w >> 1;  // 0..1
  const int wcol = w & 1;   // 0..1

  const unsigned short* Ag = Amat + (size_t)bM * ldA;
  const unsigned short* Bg = Bmat + (size_t)bN * ldB;

  const int st_row = w * 64 + (l >> 3);
  const int st_col = ((l & 7) ^ (l >> 3)) * 8;
  const int st_lds = w * 8192;

  const int rsw0 = (((l >> 4) + 0) ^ (l & 7)) * 16;
  const int rsw1 = (((l >> 4) + 4) ^ (l & 7)) * 16;
  const int arow = l & 15;

  auto stageA = [&](int k) {
    char* base = smem + (k & 1) * 32768 + st_lds;
    const unsigned short* g = Ag + (size_t)st_row * ldA + k * 64 + st_col;
#pragma unroll
    for (int i = 0; i < 8; ++i)
      gload16(g + (size_t)(i * 8) * ldA, base + i * 1024);
  };
  auto stageB = [&](int k) {
    char* base = smem + 65536 + (k & 1) * 32768 + st_lds;
    const unsigned short* g = Bg + (size_t)st_row * ldB + k * 64 + st_col;
#pragma unroll
    for (int i = 0; i < 8; ++i)
      gload16(g + (size_t)(i * 8) * ldB, base + i * 1024);
  };

  f32x4 acc[8][8] = {};

  stageA(0); stageB(0);
  __syncthreads();

  for (int k = 0; k < nt; ++k) {
    char* Abase = smem + (k & 1) * 32768;
    char* Bbase = smem + 65536 + (k & 1) * 32768;
    if (k + 1 < nt) { stageA(k + 1); stageB(k + 1); }

#pragma unroll
    for (int kk = 0; kk < 2; ++kk) {
      const int rsw = kk ? rsw1 : rsw0;
      bf16x8 af[8], bf[8];
#pragma unroll
      for (int m = 0; m < 8; ++m)
        af[m] = *(const bf16x8*)(Abase + (wrow * 128 + m * 16 + arow) * 128 + rsw);
#pragma unroll
      for (int n = 0; n < 8; ++n)
        bf[n] = *(const bf16x8*)(Bbase + (wcol * 128 + n * 16 + arow) * 128 + rsw);
#pragma unroll
      for (int m = 0; m < 8; ++m)
#pragma unroll
        for (int n = 0; n < 8; ++n)
          acc[m][n] = __builtin_amdgcn_mfma_f32_16x16x32_bf16(af[m], bf[n], acc[m][n], 0, 0, 0);
    }

    __syncthreads();
  }

  // epilogue: D row = (lane>>4)*4 + r, col = lane&15
  // cos = acc*sx*sy; fused rowsum + colsum of K = exp(10*cos)
  float syv[8];
#pragma unroll
  for (int n = 0; n < 8; ++n)
    syv[n] = sy[bN + wcol * 128 + n * 16 + (l & 15)];
  float cs[8] = {};
#pragma unroll
  for (int m = 0; m < 8; ++m) {
#pragma unroll
    for (int r = 0; r < 4; ++r) {
      const int i = bM + wrow * 128 + m * 16 + (l >> 4) * 4 + r;
      const float sxv = 1.0f / fmaxf(sqrtf(ssx[i]), 1e-8f);
      float rs = 0.0f;
#pragma unroll
      for (int n = 0; n < 8; ++n) {
        const int j = bN + wcol * 128 + n * 16 + (l & 15);
        const float kvf = __expf(10.0f * acc[m][n][r] * sxv * syv[n]);
        outKbf[(size_t)i * ldC + j] = f2bf(kvf);
        rs += kvf;
        cs[n] += kvf;
      }
      rs += __shfl_xor(rs, 1); rs += __shfl_xor(rs, 2);
      rs += __shfl_xor(rs, 4); rs += __shfl_xor(rs, 8);
      if ((l & 15) == 0) unsafeAtomicAdd(&rsum[i], rs);
    }
  }
#pragma unroll
  for (int n = 0; n < 8; ++n) {
    float c = cs[n];
    c += __shfl_xor(c, 16); c += __shfl_xor(c, 32);
    if (l < 16) {
      const int j = bN + wcol * 128 + n * 16 + l;
      unsafeAtomicAdd(&csum[j], c);
    }
  }
}

// ============ GEMM2: 256Mx128N NT, 32x32x16, frag-pipelined (frozen) =======
__global__ __launch_bounds__(256, 1) void gemm_t2(
    const unsigned short* __restrict__ Amat, const unsigned short* __restrict__ Bmat,
    int ldA, int ldB, int nt, int ldC, float* __restrict__ outC) {
  __shared__ alignas(16) char smem[98304];
  const int t = threadIdx.x;
  const int l = t & 63;
  const int w = t >> 6;  // 0..3

  const int nwg = gridDim.x * gridDim.y;
  const int lin = blockIdx.y * gridDim.x + blockIdx.x;
  const int lin2 = (lin & 7) * (nwg >> 3) + (lin >> 3);
  const int bx = lin2 % gridDim.x;   // N dir: bN = bx*128
  const int by = lin2 / gridDim.x;   // M dir: bM = by*256
  const int bM = by * 256;
  const int bN = bx * 128;
  const int wrow = w >> 1;  // 0..1 -> M offset wrow*128
  const int wcol = w & 1;   // 0..1 -> N offset wcol*64

  const unsigned short* Ag = Amat + (size_t)bM * ldA;
  const unsigned short* Bg = Bmat + (size_t)bN * ldB;

  const int stA_row = w * 64 + (l >> 3);
  const int st_col = ((l & 7) ^ (l >> 3)) * 8;
  const int stA_lds = w * 8192;
  const int stB_row = w * 32 + (l >> 3);
  const int stB_lds = w * 4096;

  const int frow = l & 31;         // fragment row/col within 32
  const int kg = l >> 5;           // k-group (0/1)
  const int xr = l & 7;            // row&7 for swizzle

  auto stageA = [&](int k) {
    char* base = smem + (k & 1) * 32768 + stA_lds;
    const unsigned short* g = Ag + (size_t)stA_row * ldA + k * 64 + st_col;
#pragma unroll
    for (int i = 0; i < 8; ++i)
      gload16(g + (size_t)(i * 8) * ldA, base + i * 1024);
  };
  auto stageB = [&](int k) {
    char* base = smem + 65536 + (k & 1) * 16384 + stB_lds;
    const unsigned short* g = Bg + (size_t)stB_row * ldB + k * 64 + st_col;
#pragma unroll
    for (int i = 0; i < 4; ++i)
      gload16(g + (size_t)(i * 8) * ldB, base + i * 1024);
  };

  f32x16 acc[4][2] = {};

  stageA(0); stageB(0);
  __syncthreads();

  for (int k = 0; k < nt; ++k) {
    char* Abase = smem + (k & 1) * 32768;
    char* Bbase = smem + 65536 + (k & 1) * 16384;
    if (k + 1 < nt) { stageA(k + 1); stageB(k + 1); }

    bf16x8 aA[4], bA[2], aB[4], bB[2];
    auto LD = [&](int kk, bf16x8 (&af)[4], bf16x8 (&bf)[2]) {
      const int rsw = ((2 * kk + kg) ^ xr) * 16;  // swizzled 16B chunk
#pragma unroll
      for (int m = 0; m < 4; ++m)
        af[m] = *(const bf16x8*)(Abase + (wrow * 128 + m * 32 + frow) * 128 + rsw);
#pragma unroll
      for (int n = 0; n < 2; ++n)
        bf[n] = *(const bf16x8*)(Bbase + (wcol * 64 + n * 32 + frow) * 128 + rsw);
    };
    auto MM = [&](bf16x8 (&af)[4], bf16x8 (&bf)[2]) {
#pragma unroll
      for (int m = 0; m < 4; ++m)
#pragma unroll
        for (int n = 0; n < 2; ++n)
          acc[m][n] = __builtin_amdgcn_mfma_f32_32x32x16_bf16(af[m], bf[n], acc[m][n], 0, 0, 0);
    };
    LD(0, aA, bA);
    LD(1, aB, bB);
    MM(aA, bA);
    LD(2, aA, bA);
    MM(aB, bB);
    LD(3, aB, bB);
    MM(aA, bA);
    MM(aB, bB);

    __syncthreads();
  }

  // epilogue: D row = (reg&3) + 8*(reg>>2) + 4*(lane>>5), col = lane&31
#pragma unroll
  for (int m = 0; m < 4; ++m)
#pragma unroll
    for (int n = 0; n < 2; ++n)
#pragma unroll
      for (int r = 0; r < 16; ++r) {
        const int i = bM + wrow * 128 + m * 32 + (r & 3) + 8 * (r >> 2) + 4 * kg;
        const int j = bN + wcol * 64 + n * 32 + frow;
        outC[(size_t)i * ldC + j] = acc[m][n][r];
      }
}

// --------------------------- sinkhorn pieces -------------------------------
__global__ __launch_bounds__(256) void zero_small(float* p) {
  p[blockIdx.x * 256 + threadIdx.x] = 0.0f;
}

// ------ T = (logK)/10 * (u K v) + delta -> bf16 (u,v inline from sums) -----
__global__ __launch_bounds__(256) void build_T(
    const unsigned short* __restrict__ Kbf,
    const float* __restrict__ delta, const float* __restrict__ rsum,
    const float* __restrict__ csum, unsigned short* __restrict__ Tbf) {
  const size_t e = ((size_t)blockIdx.x * 256 + threadIdx.x) * 8;
  const int i = (int)(e >> 12);
  const int j = (int)(e & 4095);
  const float ui = pow_fi_of(rsum[i]);
  ushort8 kv = *(const ushort8*)(Kbf + e);
  float4 d0 = *(const float4*)(delta + e);
  float4 d1 = *(const float4*)(delta + e + 4);
  float4 t0 = *(const float4*)(csum + j);
  float4 t1 = *(const float4*)(csum + j + 4);
  float v0x = pow_fi_of(t0.x), v0y = pow_fi_of(t0.y), v0z = pow_fi_of(t0.z), v0w = pow_fi_of(t0.w);
  float v1x = pow_fi_of(t1.x), v1y = pow_fi_of(t1.y), v1z = pow_fi_of(t1.z), v1w = pow_fi_of(t1.w);
  ushort8 o;
  float k0 = bf2f(kv[0]), k1 = bf2f(kv[1]), k2 = bf2f(kv[2]), k3 = bf2f(kv[3]);
  float k4 = bf2f(kv[4]), k5 = bf2f(kv[5]), k6 = bf2f(kv[6]), k7 = bf2f(kv[7]);
  o[0] = f2bf(0.1f * __logf(k0) * (ui * k0 * v0x) + d0.x);
  o[1] = f2bf(0.1f * __logf(k1) * (ui * k1 * v0y) + d0.y);
  o[2] = f2bf(0.1f * __logf(k2) * (ui * k2 * v0z) + d0.z);
  o[3] = f2bf(0.1f * __logf(k3) * (ui * k3 * v0w) + d0.w);
  o[4] = f2bf(0.1f * __logf(k4) * (ui * k4 * v1x) + d1.x);
  o[5] = f2bf(0.1f * __logf(k5) * (ui * k5 * v1y) + d1.y);
  o[6] = f2bf(0.1f * __logf(k6) * (ui * k6 * v1z) + d1.z);
  o[7] = f2bf(0.1f * __logf(k7) * (ui * k7 * v1w) + d1.w);
  *(ushort8*)(Tbf + e) = o;
}

// ---------------------------------------------------------------------------
extern "C" void kernel_launch(void* const* d_in, const int* in_sizes, int n_in,
                              void* d_out, int out_size, void* d_ws, size_t ws_size,
                              hipStream_t stream) {
  const float* X = (const float*)d_in[0];
  const float* Y = (const float*)d_in[1];
  const float* delta = (const float*)d_in[2];
  float* out = (float*)d_out;
  uint8_t* ws = (uint8_t*)d_ws;

  const size_t SZ_NN_BF = (size_t)N_TOK * N_TOK * 2;  // 32 MiB
  const size_t SZ_ND_BF = (size_t)N_TOK * D_EMB * 2;  // 16 MiB

  unsigned short* K_bf = (unsigned short*)(ws);                        // [0,32M)
  unsigned short* T_bf = (unsigned short*)(ws + SZ_NN_BF);             // [32M,64M)
  unsigned short* Xb = (unsigned short*)(ws + 2 * SZ_NN_BF);           // [64M,80M)
  unsigned short* XTb = (unsigned short*)(ws + 2 * SZ_NN_BF + SZ_ND_BF); // [80M,96M)
  float* rsum = (float*)(ws + 2 * SZ_NN_BF + 2 * SZ_ND_BF);            // [96M, +48K)
  float* csum = rsum + N_TOK;
  float* ssx = csum + N_TOK;
  float* sy = ssx + N_TOK;
  unsigned short* Yb = (unsigned short*)d_out;  // parked; overwritten by gemm_t2

  // 0) zero rsum+csum+ssx (contiguous 12288 floats)
  zero_small<<<48, 256, 0, stream>>>(rsum);
  // 1) prep: Yb=bf16(Y)+sy; Xb=bf16(X)+XTb=bf16(X)^T+ssx partials
  prep_y<<<N_TOK, 256, 0, stream>>>(Y, Yb, sy);
  prep_x<<<dim3(2, 128), 256, 0, stream>>>(X, Xb, XTb, ssx);
  // 2) K = exp(10 * cos), cos = (Xb.Yb)*sx*sy in epilogue; fused row/colsum
  gemm256w4<<<dim3(16, 16, 1), 256, 0, stream>>>(
      Xb, Yb, D_EMB, D_EMB, D_EMB / 64, N_TOK, K_bf, rsum, csum, ssx, sy);
  // 3) T = (logK)/10 * (u K v) + delta  (u,v inline from rsum,csum)
  build_T<<<(N_TOK / 8) * (N_TOK / 256), 256, 0, stream>>>(K_bf, delta, rsum, csum, T_bf);
  // 4) out = T @ X == NT(T, XTb), nt = N_TOK/64 = 64, direct stores
  gemm_t2<<<dim3(16, 16, 1), 256, 0, stream>>>(
      T_bf, XTb, N_TOK, N_TOK, N_TOK / 64, D_EMB, out);
}

// Round 22
// 198.583 us; speedup vs baseline: 1.1331x; 1.1331x over previous
//
#include <hip/hip_runtime.h>
#include <stdint.h>

// ---------------------------------------------------------------------------
// TokenAlignerOT: A = cos(X,Y); K = exp(10A); ONE unbalanced-Sinkhorn
// iteration; T = (log K)/10 * (u K v^T) + delta; out = T @ X.
// Round 22 = exact revert to r20 (session best, 198.3us) after r21's
// scale-in-epilogue regression (+27us: VGPR-capped GEMM1 epilogue spilled
// on sy/ssx staging; prep_x slower than rownorm+transpose).
// GEMM1: 256x256 NT, 16x16x32, fused exp+rowsum+colsum (86us, frozen).
// GEMM2: 256Mx128N NT, 32x32x16 frag-pipelined, direct stores (83us, frozen).
// Both at the 2-phase family plateau (~818 TF, MfmaUtil 32%) — invariant
// across 11 controlled core experiments. Workspace: 80 MiB + 16 KiB.
// ---------------------------------------------------------------------------

typedef __attribute__((ext_vector_type(8))) __bf16 bf16x8;
typedef __attribute__((ext_vector_type(4))) float f32x4;
typedef __attribute__((ext_vector_type(16))) float f32x16;
typedef __attribute__((ext_vector_type(8))) unsigned short ushort8;

#define N_TOK 4096
#define D_EMB 2048
#define FI 0.009900990099009901f   /* reg_m/(reg_m+reg) = 0.001/0.101 */
#define LOG2A (-12.0f)             /* log2(1/4096) */

__device__ __forceinline__ unsigned short f2bf(float f) {
  union { float f; uint32_t u; } c; c.f = f;
  uint32_t r = (c.u + 0x7FFFu + ((c.u >> 16) & 1u)) >> 16;
  return (unsigned short)r;
}
__device__ __forceinline__ float bf2f(unsigned short h) {
  union { uint32_t u; float f; } c; c.u = ((uint32_t)h) << 16;
  return c.f;
}
__device__ __forceinline__ float pow_fi_of(float s) {
  return exp2f(FI * (LOG2A - log2f(s)));
}

// async global->LDS, 16 B per lane; LDS dest is wave-uniform base (+lane*16 HW)
typedef const __attribute__((address_space(1))) unsigned int* as1_u32p;
typedef __attribute__((address_space(3))) unsigned int* as3_u32p;
__device__ __forceinline__ void gload16(const void* g, void* l) {
  __builtin_amdgcn_global_load_lds((as1_u32p)g, (as3_u32p)l, 16, 0, 0);
}

// --------------- row L2-normalize -> bf16 (X and Y in one grid) ------------
__global__ __launch_bounds__(256) void rownorm_all(
    const float* __restrict__ X, const float* __restrict__ Y,
    unsigned short* __restrict__ Xn, unsigned short* __restrict__ Yn) {
  const int row = blockIdx.x & 4095;
  const int isY = blockIdx.x >> 12;
  const int t = threadIdx.x;
  const float* r = (isY ? Y : X) + (size_t)row * D_EMB;
  float4 a = *(const float4*)(r + t * 8);
  float4 b = *(const float4*)(r + t * 8 + 4);
  float s = a.x * a.x + a.y * a.y + a.z * a.z + a.w * a.w
          + b.x * b.x + b.y * b.y + b.z * b.z + b.w * b.w;
#pragma unroll
  for (int off = 32; off; off >>= 1) s += __shfl_xor(s, off);
  __shared__ float wsum[4];
  if ((t & 63) == 0) wsum[t >> 6] = s;
  __syncthreads();
  float tot = wsum[0] + wsum[1] + wsum[2] + wsum[3];
  float scale = 1.0f / fmaxf(sqrtf(tot), 1e-8f);
  ushort8 o;
  o[0] = f2bf(a.x * scale); o[1] = f2bf(a.y * scale);
  o[2] = f2bf(a.z * scale); o[3] = f2bf(a.w * scale);
  o[4] = f2bf(b.x * scale); o[5] = f2bf(b.y * scale);
  o[6] = f2bf(b.z * scale); o[7] = f2bf(b.w * scale);
  unsigned short* outn = isY ? Yn : Xn;
  *(ushort8*)(outn + (size_t)row * D_EMB + t * 8) = o;
}

// --------------------------- transpose X -> bf16 X^T ------------------------
__global__ __launch_bounds__(256) void transpose_f32_to_bf16(
    const float* __restrict__ in, unsigned short* __restrict__ out, int R, int C) {
  __shared__ float tile[32][33];
  const int bi = blockIdx.y * 32, bj = blockIdx.x * 32;
  const int tx = threadIdx.x, ty = threadIdx.y;
#pragma unroll
  for (int dy = 0; dy < 32; dy += 8)
    tile[ty + dy][tx] = in[(size_t)(bi + ty + dy) * C + bj + tx];
  __syncthreads();
#pragma unroll
  for (int dy = 0; dy < 32; dy += 8)
    out[(size_t)(bj + ty + dy) * R + bi + tx] = f2bf(tile[tx][ty + dy]);
}

// ============ GEMM1: 256x256 NT, 4 waves, 128x128/wave (frozen core) =======
// Epilogue: K = bf16(exp(10*C)) + fused rowsum AND colsum atomics.
__global__ __launch_bounds__(256, 1) void gemm256w4(
    const unsigned short* __restrict__ Amat, const unsigned short* __restrict__ Bmat,
    int ldA, int ldB, int nt, int ldC,
    unsigned short* __restrict__ outKbf, float* __restrict__ rsum,
    float* __restrict__ csum) {
  __shared__ alignas(16) char smem[131072];
  const int t = threadIdx.x;
  const int l = t & 63;
  const int w = t >> 6;  // 0..3

  const int nwg = gridDim.x * gridDim.y;
  const int lin = blockIdx.y * gridDim.x + blockIdx.x;
  const int lin2 = (lin & 7) * (nwg >> 3) + (lin >> 3);
  const int bx = lin2 % gridDim.x;
  const int by = lin2 / gridDim.x;
  const int bM = by * 256;
  const int bN = bx * 256;
  const int wrow = w >> 1;  // 0..1
  const int wcol = w & 1;   // 0..1

  const unsigned short* Ag = Amat + (size_t)bM * ldA;
  const unsigned short* Bg = Bmat + (size_t)bN * ldB;

  const int st_row = w * 64 + (l >> 3);
  const int st_col = ((l & 7) ^ (l >> 3)) * 8;
  const int st_lds = w * 8192;

  const int rsw0 = (((l >> 4) + 0) ^ (l & 7)) * 16;
  const int rsw1 = (((l >> 4) + 4) ^ (l & 7)) * 16;
  const int arow = l & 15;

  auto stageA = [&](int k) {
    char* base = smem + (k & 1) * 32768 + st_lds;
    const unsigned short* g = Ag + (size_t)st_row * ldA + k * 64 + st_col;
#pragma unroll
    for (int i = 0; i < 8; ++i)
      gload16(g + (size_t)(i * 8) * ldA, base + i * 1024);
  };
  auto stageB = [&](int k) {
    char* base = smem + 65536 + (k & 1) * 32768 + st_lds;
    const unsigned short* g = Bg + (size_t)st_row * ldB + k * 64 + st_col;
#pragma unroll
    for (int i = 0; i < 8; ++i)
      gload16(g + (size_t)(i * 8) * ldB, base + i * 1024);
  };

  f32x4 acc[8][8] = {};

  stageA(0); stageB(0);
  __syncthreads();

  for (int k = 0; k < nt; ++k) {
    char* Abase = smem + (k & 1) * 32768;
    char* Bbase = smem + 65536 + (k & 1) * 32768;
    if (k + 1 < nt) { stageA(k + 1); stageB(k + 1); }

#pragma unroll
    for (int kk = 0; kk < 2; ++kk) {
      const int rsw = kk ? rsw1 : rsw0;
      bf16x8 af[8], bf[8];
#pragma unroll
      for (int m = 0; m < 8; ++m)
        af[m] = *(const bf16x8*)(Abase + (wrow * 128 + m * 16 + arow) * 128 + rsw);
#pragma unroll
      for (int n = 0; n < 8; ++n)
        bf[n] = *(const bf16x8*)(Bbase + (wcol * 128 + n * 16 + arow) * 128 + rsw);
#pragma unroll
      for (int m = 0; m < 8; ++m)
#pragma unroll
        for (int n = 0; n < 8; ++n)
          acc[m][n] = __builtin_amdgcn_mfma_f32_16x16x32_bf16(af[m], bf[n], acc[m][n], 0, 0, 0);
    }

    __syncthreads();
  }

  // epilogue: D row = (lane>>4)*4 + r, col = lane&15
  // fused rowsum (shfl over l&15) + colsum (cs[8] -> shfl over l>>4)
  float cs[8] = {};
#pragma unroll
  for (int m = 0; m < 8; ++m) {
#pragma unroll
    for (int r = 0; r < 4; ++r) {
      const int i = bM + wrow * 128 + m * 16 + (l >> 4) * 4 + r;
      float rs = 0.0f;
#pragma unroll
      for (int n = 0; n < 8; ++n) {
        const int j = bN + wcol * 128 + n * 16 + (l & 15);
        const float kvf = __expf(10.0f * acc[m][n][r]);
        outKbf[(size_t)i * ldC + j] = f2bf(kvf);
        rs += kvf;
        cs[n] += kvf;
      }
      rs += __shfl_xor(rs, 1); rs += __shfl_xor(rs, 2);
      rs += __shfl_xor(rs, 4); rs += __shfl_xor(rs, 8);
      if ((l & 15) == 0) unsafeAtomicAdd(&rsum[i], rs);
    }
  }
#pragma unroll
  for (int n = 0; n < 8; ++n) {
    float c = cs[n];
    c += __shfl_xor(c, 16); c += __shfl_xor(c, 32);
    if (l < 16) {
      const int j = bN + wcol * 128 + n * 16 + l;
      unsafeAtomicAdd(&csum[j], c);
    }
  }
}

// ============ GEMM2: 256Mx128N NT, 32x32x16, frag-pipelined (frozen) =======
__global__ __launch_bounds__(256, 1) void gemm_t2(
    const unsigned short* __restrict__ Amat, const unsigned short* __restrict__ Bmat,
    int ldA, int ldB, int nt, int ldC, float* __restrict__ outC) {
  __shared__ alignas(16) char smem[98304];
  const int t = threadIdx.x;
  const int l = t & 63;
  const int w = t >> 6;  // 0..3

  const int nwg = gridDim.x * gridDim.y;
  const int lin = blockIdx.y * gridDim.x + blockIdx.x;
  const int lin2 = (lin & 7) * (nwg >> 3) + (lin >> 3);
  const int bx = lin2 % gridDim.x;   // N dir: bN = bx*128
  const int by = lin2 / gridDim.x;   // M dir: bM = by*256
  const int bM = by * 256;
  const int bN = bx * 128;
  const int wrow = w >> 1;  // 0..1 -> M offset wrow*128
  const int wcol = w & 1;   // 0..1 -> N offset wcol*64

  const unsigned short* Ag = Amat + (size_t)bM * ldA;
  const unsigned short* Bg = Bmat + (size_t)bN * ldB;

  const int stA_row = w * 64 + (l >> 3);
  const int st_col = ((l & 7) ^ (l >> 3)) * 8;
  const int stA_lds = w * 8192;
  const int stB_row = w * 32 + (l >> 3);
  const int stB_lds = w * 4096;

  const int frow = l & 31;         // fragment row/col within 32
  const int kg = l >> 5;           // k-group (0/1)
  const int xr = l & 7;            // row&7 for swizzle

  auto stageA = [&](int k) {
    char* base = smem + (k & 1) * 32768 + stA_lds;
    const unsigned short* g = Ag + (size_t)stA_row * ldA + k * 64 + st_col;
#pragma unroll
    for (int i = 0; i < 8; ++i)
      gload16(g + (size_t)(i * 8) * ldA, base + i * 1024);
  };
  auto stageB = [&](int k) {
    char* base = smem + 65536 + (k & 1) * 16384 + stB_lds;
    const unsigned short* g = Bg + (size_t)stB_row * ldB + k * 64 + st_col;
#pragma unroll
    for (int i = 0; i < 4; ++i)
      gload16(g + (size_t)(i * 8) * ldB, base + i * 1024);
  };

  f32x16 acc[4][2] = {};

  stageA(0); stageB(0);
  __syncthreads();

  for (int k = 0; k < nt; ++k) {
    char* Abase = smem + (k & 1) * 32768;
    char* Bbase = smem + 65536 + (k & 1) * 16384;
    if (k + 1 < nt) { stageA(k + 1); stageB(k + 1); }

    bf16x8 aA[4], bA[2], aB[4], bB[2];
    auto LD = [&](int kk, bf16x8 (&af)[4], bf16x8 (&bf)[2]) {
      const int rsw = ((2 * kk + kg) ^ xr) * 16;  // swizzled 16B chunk
#pragma unroll
      for (int m = 0; m < 4; ++m)
        af[m] = *(const bf16x8*)(Abase + (wrow * 128 + m * 32 + frow) * 128 + rsw);
#pragma unroll
      for (int n = 0; n < 2; ++n)
        bf[n] = *(const bf16x8*)(Bbase + (wcol * 64 + n * 32 + frow) * 128 + rsw);
    };
    auto MM = [&](bf16x8 (&af)[4], bf16x8 (&bf)[2]) {
#pragma unroll
      for (int m = 0; m < 4; ++m)
#pragma unroll
        for (int n = 0; n < 2; ++n)
          acc[m][n] = __builtin_amdgcn_mfma_f32_32x32x16_bf16(af[m], bf[n], acc[m][n], 0, 0, 0);
    };
    LD(0, aA, bA);
    LD(1, aB, bB);
    MM(aA, bA);
    LD(2, aA, bA);
    MM(aB, bB);
    LD(3, aB, bB);
    MM(aA, bA);
    MM(aB, bB);

    __syncthreads();
  }

  // epilogue: D row = (reg&3) + 8*(reg>>2) + 4*(lane>>5), col = lane&31
#pragma unroll
  for (int m = 0; m < 4; ++m)
#pragma unroll
    for (int n = 0; n < 2; ++n)
#pragma unroll
      for (int r = 0; r < 16; ++r) {
        const int i = bM + wrow * 128 + m * 32 + (r & 3) + 8 * (r >> 2) + 4 * kg;
        const int j = bN + wcol * 64 + n * 32 + frow;
        outC[(size_t)i * ldC + j] = acc[m][n][r];
      }
}

// --------------------------- sinkhorn pieces -------------------------------
__global__ __launch_bounds__(256) void zero_small(float* p) {
  p[blockIdx.x * 256 + threadIdx.x] = 0.0f;
}

// ------ T = (logK)/10 * (u K v) + delta -> bf16 (u,v inline from sums) -----
__global__ __launch_bounds__(256) void build_T(
    const unsigned short* __restrict__ Kbf,
    const float* __restrict__ delta, const float* __restrict__ rsum,
    const float* __restrict__ csum, unsigned short* __restrict__ Tbf) {
  const size_t e = ((size_t)blockIdx.x * 256 + threadIdx.x) * 8;
  const int i = (int)(e >> 12);
  const int j = (int)(e & 4095);
  const float ui = pow_fi_of(rsum[i]);
  ushort8 kv = *(const ushort8*)(Kbf + e);
  float4 d0 = *(const float4*)(delta + e);
  float4 d1 = *(const float4*)(delta + e + 4);
  float4 t0 = *(const float4*)(csum + j);
  float4 t1 = *(const float4*)(csum + j + 4);
  float v0x = pow_fi_of(t0.x), v0y = pow_fi_of(t0.y), v0z = pow_fi_of(t0.z), v0w = pow_fi_of(t0.w);
  float v1x = pow_fi_of(t1.x), v1y = pow_fi_of(t1.y), v1z = pow_fi_of(t1.z), v1w = pow_fi_of(t1.w);
  ushort8 o;
  float k0 = bf2f(kv[0]), k1 = bf2f(kv[1]), k2 = bf2f(kv[2]), k3 = bf2f(kv[3]);
  float k4 = bf2f(kv[4]), k5 = bf2f(kv[5]), k6 = bf2f(kv[6]), k7 = bf2f(kv[7]);
  o[0] = f2bf(0.1f * __logf(k0) * (ui * k0 * v0x) + d0.x);
  o[1] = f2bf(0.1f * __logf(k1) * (ui * k1 * v0y) + d0.y);
  o[2] = f2bf(0.1f * __logf(k2) * (ui * k2 * v0z) + d0.z);
  o[3] = f2bf(0.1f * __logf(k3) * (ui * k3 * v0w) + d0.w);
  o[4] = f2bf(0.1f * __logf(k4) * (ui * k4 * v1x) + d1.x);
  o[5] = f2bf(0.1f * __logf(k5) * (ui * k5 * v1y) + d1.y);
  o[6] = f2bf(0.1f * __logf(k6) * (ui * k6 * v1z) + d1.z);
  o[7] = f2bf(0.1f * __logf(k7) * (ui * k7 * v1w) + d1.w);
  *(ushort8*)(Tbf + e) = o;
}

// ---------------------------------------------------------------------------
extern "C" void kernel_launch(void* const* d_in, const int* in_sizes, int n_in,
                              void* d_out, int out_size, void* d_ws, size_t ws_size,
                              hipStream_t stream) {
  const float* X = (const float*)d_in[0];
  const float* Y = (const float*)d_in[1];
  const float* delta = (const float*)d_in[2];
  float* out = (float*)d_out;
  uint8_t* ws = (uint8_t*)d_ws;

  const size_t SZ_NN_BF = (size_t)N_TOK * N_TOK * 2;  // 32 MiB
  const size_t SZ_ND_BF = (size_t)N_TOK * D_EMB * 2;  // 16 MiB

  unsigned short* K_bf = (unsigned short*)(ws);                  // [0,32M)
  unsigned short* T_bf = (unsigned short*)(ws + SZ_NN_BF);       // [32M,64M)
  unsigned short* Xn = (unsigned short*)(ws + 2 * SZ_NN_BF);     // [64M,80M)
  unsigned short* XT = Xn;                                       // Xn dead after GEMM1
  float* rsum = (float*)(ws + 2 * SZ_NN_BF + SZ_ND_BF);          // [80M, +16K)
  float* csum = rsum + N_TOK;
  unsigned short* Yn = (unsigned short*)d_out;  // parked; overwritten by gemm_t2

  // 0) zero rsum+csum (contiguous 8192 floats)
  zero_small<<<32, 256, 0, stream>>>(rsum);
  // 1) normalize rows -> bf16 (X and Y in one merged launch)
  rownorm_all<<<2 * N_TOK, 256, 0, stream>>>(X, Y, Xn, Yn);
  // 2) K = exp(10 * Xn @ Yn^T), fused rowsum + colsum atomics
  gemm256w4<<<dim3(16, 16, 1), 256, 0, stream>>>(
      Xn, Yn, D_EMB, D_EMB, D_EMB / 64, N_TOK, K_bf, rsum, csum);
  // 3) XT = bf16(X^T)  (overwrites Xn slot, dead after GEMM1)
  transpose_f32_to_bf16<<<dim3(D_EMB / 32, N_TOK / 32), dim3(32, 8), 0, stream>>>(
      X, XT, N_TOK, D_EMB);
  // 4) T = (logK)/10 * (u K v) + delta  (u,v inline from rsum,csum)
  build_T<<<(N_TOK / 8) * (N_TOK / 256), 256, 0, stream>>>(K_bf, delta, rsum, csum, T_bf);
  // 5) out = T @ X == NT(T, X^T), nt = N_TOK/64 = 64, direct stores
  gemm_t2<<<dim3(16, 16, 1), 256, 0, stream>>>(
      T_bf, XT, N_TOK, N_TOK, N_TOK / 64, D_EMB, out);
}